// Round 2
// baseline (134.690 us; speedup 1.0000x reference)
//
#include <hip/hip_runtime.h>

// inputs: [M=4096, N=16384] fp32 logits; targets: [M] int32; k = int(0.01*(N-1)) = 163
#define M        4096
#define N        16384
#define K_SEL    163
#define DELTA_W  5.0f
#define NT       256
#define EPT      64            // N / NT
#define CAP      2048          // LDS candidate-list capacity (Gaussian: ~372 +- 19 per row)
#define COPIES   8             // histogram privatization copies
#define SCALE    4096.0f       // fixed-point scale for order-independent sum (err ~1.2e-4)
#define THRESH   2.0f          // candidate filter: P(x>=2) * 16384 ~= 372 >> 163

// Order-preserving float<->uint32 key (ascending float <-> ascending key)
__device__ __forceinline__ unsigned f2key(float x) {
    unsigned u = __float_as_uint(x);
    return u ^ ((unsigned)((int)u >> 31) | 0x80000000u);
}
__device__ __forceinline__ float key2f(unsigned k) {
    unsigned u = k ^ (~(unsigned)((int)k >> 31) | 0x80000000u);
    return __uint_as_float(u);
}

// Scan 256-bin privatized histogram (s_cnt already filled, barrier'd), pick the
// bin where the cumulative-from-top count crosses kr, narrow prefix/krem.
// Uniform control flow; contains __syncthreads.
__device__ __forceinline__ void select_bin(
    unsigned* s_cnt, unsigned* s_waveTot, unsigned* s_prefix, unsigned* s_krem,
    int tid, int lane, int wv, unsigned prefix, unsigned kr)
{
    unsigned bc = 0;
    #pragma unroll
    for (int c = 0; c < COPIES; ++c) bc += s_cnt[tid * COPIES + c];
    unsigned suf = bc;                          // inclusive suffix-scan of 64-bin chunk
    #pragma unroll
    for (int off = 1; off < 64; off <<= 1) {
        unsigned o = __shfl_down(suf, off);
        suf += (lane + off < 64) ? o : 0u;
    }
    if (lane == 0) s_waveTot[wv] = suf;
    __syncthreads();
    unsigned above = 0;
    for (int w = wv + 1; w < 4; ++w) above += s_waveTot[w];
    unsigned S   = suf + above;                 // elems in bins >= tid
    unsigned abv = S - bc;                      // elems in bins >  tid
    if (abv < kr && S >= kr) {                  // exactly one bin satisfies
        *s_prefix = (prefix << 8) | (unsigned)tid;
        *s_krem   = kr - abv;
    }
    __syncthreads();
}

__global__ __launch_bounds__(NT) void row_loss_kernel(
    const float* __restrict__ inp, const int* __restrict__ tgt,
    float* __restrict__ row_loss)
{
    const int row  = blockIdx.x;
    const int tid  = threadIdx.x;
    const int lane = tid & 63;
    const int wv   = tid >> 6;
    const float* rp = inp + (size_t)row * N;
    const int target = tgt[row];

    __shared__ unsigned s_list[CAP];
    __shared__ unsigned s_cnt[256 * COPIES];
    __shared__ unsigned s_waveTot[4];
    __shared__ unsigned s_listN;
    __shared__ unsigned s_prefix, s_krem;
    __shared__ int s_isum;

    if (tid == 0) { s_listN = 0u; s_isum = 0; }
    __syncthreads();

    // ---- Phase 1: stream row once; wave-aggregated push of candidates ----
    const float4* rp4 = reinterpret_cast<const float4*>(rp);
    #pragma unroll 4
    for (int i = 0; i < EPT / 4; ++i) {
        float4 v = rp4[i * NT + tid];
        const int base = (i * NT + tid) * 4;
        #pragma unroll
        for (int j = 0; j < 4; ++j) {
            float x = (j == 0) ? v.x : (j == 1) ? v.y : (j == 2) ? v.z : v.w;
            bool pred = (x >= THRESH) && (base + j != target);
            unsigned long long mk = __ballot(pred);
            if (pred) {
                int leader = __builtin_ctzll(mk);
                unsigned pos = (unsigned)__popcll(mk & ((1ull << lane) - 1ull));
                unsigned bidx = 0;
                if (lane == leader) bidx = atomicAdd(&s_listN, (unsigned)__popcll(mk));
                bidx = __shfl(bidx, leader);
                unsigned idx = bidx + pos;
                if (idx < CAP) s_list[idx] = f2key(x);
            }
        }
    }
    __syncthreads();
    const unsigned CHI = s_listN;   // exact count of candidates (increments not capped)

    unsigned tkey, krem;

    if (CHI >= K_SEL && CHI <= CAP) {
        // ---- Main path: 4-pass radix select over the small candidate list ----
        if (tid == 0) { s_prefix = 0u; s_krem = K_SEL; }
        for (int pass = 0; pass < 4; ++pass) {
            for (int i = tid; i < 256 * COPIES; i += NT) s_cnt[i] = 0u;
            __syncthreads();
            const unsigned prefix = s_prefix;
            const unsigned kr     = s_krem;
            const int shift = 24 - 8 * pass;
            for (unsigned i = tid; i < CHI; i += NT) {
                unsigned k = s_list[i];
                bool m = (pass == 0) || ((k >> (shift + 8)) == prefix);
                if (m) atomicAdd(&s_cnt[((k >> shift) & 0xFFu) * COPIES + (tid & (COPIES - 1))], 1u);
            }
            __syncthreads();
            select_bin(s_cnt, s_waveTot, &s_prefix, &s_krem, tid, lane, wv, prefix, kr);
        }
        tkey = s_prefix; krem = s_krem;

        // Order-independent (fixed-point) sum of (v+1)^2 over keys > tkey.
        int acc = 0;
        for (unsigned i = tid; i < CHI; i += NT) {
            unsigned k = s_list[i];
            if (k > tkey) { float w = key2f(k) + 1.0f; acc += (int)(w * w * SCALE + 0.5f); }
        }
        if (acc) atomicAdd(&s_isum, acc);
        __syncthreads();
    } else {
        // ---- Fallback: exact full-row radix via global re-reads (never taken
        // for the bench's Gaussian data; correctness for arbitrary inputs) ----
        if (tid == 0) { s_prefix = 0u; s_krem = K_SEL; }
        for (int pass = 0; pass < 4; ++pass) {
            for (int i = tid; i < 256 * COPIES; i += NT) s_cnt[i] = 0u;
            __syncthreads();
            const unsigned prefix = s_prefix;
            const unsigned kr     = s_krem;
            const int shift = 24 - 8 * pass;
            for (int i = 0; i < EPT / 4; ++i) {
                float4 v = rp4[i * NT + tid];
                const int base = (i * NT + tid) * 4;
                #pragma unroll
                for (int j = 0; j < 4; ++j) {
                    float x = (j == 0) ? v.x : (j == 1) ? v.y : (j == 2) ? v.z : v.w;
                    unsigned k = f2key(x);
                    if (base + j == target) k = 0u;    // mask positive to min key
                    bool m = (pass == 0) || ((k >> (shift + 8)) == prefix);
                    if (m) atomicAdd(&s_cnt[((k >> shift) & 0xFFu) * COPIES + (tid & (COPIES - 1))], 1u);
                }
            }
            __syncthreads();
            select_bin(s_cnt, s_waveTot, &s_prefix, &s_krem, tid, lane, wv, prefix, kr);
        }
        tkey = s_prefix; krem = s_krem;

        int acc = 0;
        for (int i = 0; i < EPT / 4; ++i) {
            float4 v = rp4[i * NT + tid];
            const int base = (i * NT + tid) * 4;
            #pragma unroll
            for (int j = 0; j < 4; ++j) {
                float x = (j == 0) ? v.x : (j == 1) ? v.y : (j == 2) ? v.z : v.w;
                unsigned k = f2key(x);
                if (base + j == target) k = 0u;
                if (k > tkey) { float w = key2f(k) + 1.0f; acc += (int)(w * w * SCALE + 0.5f); }
            }
        }
        if (acc) atomicAdd(&s_isum, acc);
        __syncthreads();
    }

    if (tid == 0) {
        float tv    = key2f(tkey) + 1.0f;
        float total = (float)s_isum * (1.0f / SCALE) + (float)krem * tv * tv; // + tie fixup
        float pos   = rp[target];
        float pd    = pos - 1.0f;
        row_loss[row] = DELTA_W * pd * pd + total * (1.0f / (float)K_SEL);
    }
}

__global__ __launch_bounds__(256) void final_reduce(
    const float* __restrict__ rl, float* __restrict__ out)
{
    int tid = threadIdx.x;
    float s = 0.0f;
    for (int i = tid; i < M; i += 256) s += rl[i];
    __shared__ float wp[4];
    int lane = tid & 63, wv = tid >> 6;
    #pragma unroll
    for (int off = 32; off > 0; off >>= 1) s += __shfl_down(s, off);
    if (lane == 0) wp[wv] = s;
    __syncthreads();
    if (tid == 0) out[0] = (wp[0] + wp[1] + wp[2] + wp[3]) / (float)M;
}

extern "C" void kernel_launch(void* const* d_in, const int* in_sizes, int n_in,
                              void* d_out, int out_size, void* d_ws, size_t ws_size,
                              hipStream_t stream) {
    const float* inp = (const float*)d_in[0];
    const int*   tgt = (const int*)d_in[1];
    float* out      = (float*)d_out;
    float* row_loss = (float*)d_ws;

    row_loss_kernel<<<M, NT, 0, stream>>>(inp, tgt, row_loss);
    final_reduce<<<1, 256, 0, stream>>>(row_loss, out);
}

// Round 3
// 115.089 us; speedup vs baseline: 1.1703x; 1.1703x over previous
//
#include <hip/hip_runtime.h>

// inputs: [M=4096, N=16384] fp32 logits; targets: [M] int32; k = int(0.01*(N-1)) = 163
#define M        4096
#define N        16384
#define K_SEL    163
#define DELTA_W  5.0f
#define NT       256
#define EPT      64            // N / NT
#define CAP      1024          // LDS candidate capacity (Gaussian: ~372 +- 19 per row)
#define COPIES   4             // histogram privatization copies
#define SCALE    4096.0f       // fixed-point scale: order-independent sum, err ~1e-4 << 0.47
#define THRESH   2.0f          // candidate filter: E[count(x>=2)] = 373, 11 sigma above 163

// Order-preserving float<->uint32 key (ascending float <-> ascending key)
__device__ __forceinline__ unsigned f2key(float x) {
    unsigned u = __float_as_uint(x);
    return u ^ ((unsigned)((int)u >> 31) | 0x80000000u);
}
__device__ __forceinline__ float key2f(unsigned k) {
    unsigned u = k ^ (~(unsigned)((int)k >> 31) | 0x80000000u);
    return __uint_as_float(u);
}

// Pick the bin where cumulative-from-top crosses kr; narrow prefix/krem.
// s_cnt must be filled + barrier'd. Uniform control flow; contains barriers.
__device__ __forceinline__ void select_bin(
    unsigned* s_cnt, unsigned* s_waveTot, unsigned* s_prefix, unsigned* s_krem,
    int tid, int lane, int wv, unsigned prefix, unsigned kr)
{
    unsigned bc = 0;
    #pragma unroll
    for (int c = 0; c < COPIES; ++c) bc += s_cnt[tid * COPIES + c];
    unsigned suf = bc;                          // inclusive suffix-scan of 64-bin chunk
    #pragma unroll
    for (int off = 1; off < 64; off <<= 1) {
        unsigned o = __shfl_down(suf, off);
        suf += (lane + off < 64) ? o : 0u;
    }
    if (lane == 0) s_waveTot[wv] = suf;
    __syncthreads();
    unsigned above = 0;
    for (int w = wv + 1; w < 4; ++w) above += s_waveTot[w];
    unsigned S   = suf + above;                 // elems in bins >= tid
    unsigned abv = S - bc;                      // elems in bins >  tid
    if (abv < kr && S >= kr) {                  // exactly one bin satisfies
        *s_prefix = (prefix << 8) | (unsigned)tid;
        *s_krem   = kr - abv;
    }
    __syncthreads();
}

__global__ __launch_bounds__(NT) void row_loss_kernel(
    const float* __restrict__ inp, const int* __restrict__ tgt,
    float* __restrict__ row_loss)
{
    const int row  = blockIdx.x;
    const int tid  = threadIdx.x;
    const int lane = tid & 63;
    const int wv   = tid >> 6;
    const float* rp = inp + (size_t)row * N;
    const int target = tgt[row];

    __shared__ unsigned s_list[CAP];            // 4 KiB
    __shared__ unsigned s_cnt[256 * COPIES];    // 4 KiB
    __shared__ unsigned s_waveTot[4];
    __shared__ unsigned s_listN;
    __shared__ unsigned s_prefix, s_krem;
    __shared__ int s_isum;

    if (tid == 0) { s_listN = 0u; s_isum = 0; }
    __syncthreads();

    // ---- Phase 1: stream row once. Common case per element: cmp + skip. ----
    const float4* rp4 = reinterpret_cast<const float4*>(rp);
    for (int i = 0; i < EPT / 4; ++i) {
        float4 v = rp4[i * NT + tid];
        const int base = (i * NT + tid) * 4;
        if (v.x >= THRESH || v.y >= THRESH || v.z >= THRESH || v.w >= THRESH) {
            #pragma unroll
            for (int j = 0; j < 4; ++j) {
                float x = (j == 0) ? v.x : (j == 1) ? v.y : (j == 2) ? v.z : v.w;
                if (x >= THRESH && (base + j) != target) {
                    unsigned idx = atomicAdd(&s_listN, 1u);   // plain push, no ballot
                    if (idx < CAP) s_list[idx] = f2key(x);
                }
            }
        }
    }
    __syncthreads();
    const unsigned CHI = s_listN;   // exact candidate count (increments never capped)

    unsigned tkey, krem;

    if (CHI >= K_SEL && CHI <= CAP) {
        // ---- Main path: 4-pass radix select over the small candidate list ----
        if (tid == 0) { s_prefix = 0u; s_krem = K_SEL; }
        for (int pass = 0; pass < 4; ++pass) {
            for (int i = tid; i < 256 * COPIES; i += NT) s_cnt[i] = 0u;
            __syncthreads();
            const unsigned prefix = s_prefix;
            const unsigned kr     = s_krem;
            const int shift = 24 - 8 * pass;
            for (unsigned i = tid; i < CHI; i += NT) {
                unsigned k = s_list[i];
                bool m = (pass == 0) || ((k >> (shift + 8)) == prefix);
                if (m) atomicAdd(&s_cnt[((k >> shift) & 0xFFu) * COPIES + (tid & (COPIES - 1))], 1u);
            }
            __syncthreads();
            select_bin(s_cnt, s_waveTot, &s_prefix, &s_krem, tid, lane, wv, prefix, kr);
        }
        tkey = s_prefix; krem = s_krem;

        // Order-independent (fixed-point) sum of (v+1)^2 over keys > tkey.
        int acc = 0;
        for (unsigned i = tid; i < CHI; i += NT) {
            unsigned k = s_list[i];
            if (k > tkey) { float w = key2f(k) + 1.0f; acc += (int)(w * w * SCALE + 0.5f); }
        }
        if (acc) atomicAdd(&s_isum, acc);
        __syncthreads();
    } else {
        // ---- Fallback: exact full-row radix via global re-reads (never taken
        // for the bench's Gaussian data; correctness for arbitrary inputs) ----
        if (tid == 0) { s_prefix = 0u; s_krem = K_SEL; }
        for (int pass = 0; pass < 4; ++pass) {
            for (int i = tid; i < 256 * COPIES; i += NT) s_cnt[i] = 0u;
            __syncthreads();
            const unsigned prefix = s_prefix;
            const unsigned kr     = s_krem;
            const int shift = 24 - 8 * pass;
            for (int i = 0; i < EPT / 4; ++i) {
                float4 v = rp4[i * NT + tid];
                const int base = (i * NT + tid) * 4;
                #pragma unroll
                for (int j = 0; j < 4; ++j) {
                    float x = (j == 0) ? v.x : (j == 1) ? v.y : (j == 2) ? v.z : v.w;
                    unsigned k = f2key(x);
                    if (base + j == target) k = 0u;    // mask positive to min key
                    bool m = (pass == 0) || ((k >> (shift + 8)) == prefix);
                    if (m) atomicAdd(&s_cnt[((k >> shift) & 0xFFu) * COPIES + (tid & (COPIES - 1))], 1u);
                }
            }
            __syncthreads();
            select_bin(s_cnt, s_waveTot, &s_prefix, &s_krem, tid, lane, wv, prefix, kr);
        }
        tkey = s_prefix; krem = s_krem;

        int acc = 0;
        for (int i = 0; i < EPT / 4; ++i) {
            float4 v = rp4[i * NT + tid];
            const int base = (i * NT + tid) * 4;
            #pragma unroll
            for (int j = 0; j < 4; ++j) {
                float x = (j == 0) ? v.x : (j == 1) ? v.y : (j == 2) ? v.z : v.w;
                unsigned k = f2key(x);
                if (base + j == target) k = 0u;
                if (k > tkey) { float w = key2f(k) + 1.0f; acc += (int)(w * w * SCALE + 0.5f); }
            }
        }
        if (acc) atomicAdd(&s_isum, acc);
        __syncthreads();
    }

    if (tid == 0) {
        float tv    = key2f(tkey) + 1.0f;
        float total = (float)s_isum * (1.0f / SCALE) + (float)krem * tv * tv; // + tie fixup
        float pos   = rp[target];
        float pd    = pos - 1.0f;
        row_loss[row] = DELTA_W * pd * pd + total * (1.0f / (float)K_SEL);
    }
}

__global__ __launch_bounds__(256) void final_reduce(
    const float* __restrict__ rl, float* __restrict__ out)
{
    int tid = threadIdx.x;
    float s = 0.0f;
    for (int i = tid; i < M; i += 256) s += rl[i];
    __shared__ float wp[4];
    int lane = tid & 63, wv = tid >> 6;
    #pragma unroll
    for (int off = 32; off > 0; off >>= 1) s += __shfl_down(s, off);
    if (lane == 0) wp[wv] = s;
    __syncthreads();
    if (tid == 0) out[0] = (wp[0] + wp[1] + wp[2] + wp[3]) / (float)M;
}

extern "C" void kernel_launch(void* const* d_in, const int* in_sizes, int n_in,
                              void* d_out, int out_size, void* d_ws, size_t ws_size,
                              hipStream_t stream) {
    const float* inp = (const float*)d_in[0];
    const int*   tgt = (const int*)d_in[1];
    float* out      = (float*)d_out;
    float* row_loss = (float*)d_ws;

    row_loss_kernel<<<M, NT, 0, stream>>>(inp, tgt, row_loss);
    final_reduce<<<1, 256, 0, stream>>>(row_loss, out);
}